// Round 4
// baseline (180.572 us; speedup 1.0000x reference)
//
#include <hip/hip_runtime.h>

// N=8192 nodes, D=512, E=262144. NEG=-1e6 => exp underflows to exactly 0,
// so softmax is EXACTLY sparse over each row's neighbor set (bitmask dedupes
// duplicate edges, matching .at[].set(1.0) idempotence).
//
// R4: attn = 4 mask-slices per row (wave per slice, online-softmax merge) for
//     4x wave oversubscription; gemm gets XCD-aware swizzle so each XCD's
//     A+B working set (2.5 MB) stays L2-resident; memset folded into prep1.

#define N_NODES 8192
#define DIM 512
#define MASK_WORDS 256   // 8192 bits / 32
#define SCAP 256         // per-slice neighbor chunk capacity

typedef __attribute__((ext_vector_type(8))) short short8;
typedef __attribute__((ext_vector_type(4))) float f32x4;

__device__ __forceinline__ unsigned short f2bf(float f) {
    unsigned int u = __float_as_uint(f);
    u += 0x7fffu + ((u >> 16) & 1u);          // round-to-nearest-even
    return (unsigned short)(u >> 16);
}
__device__ __forceinline__ float bf_lo(unsigned int w) { return __uint_as_float(w << 16); }
__device__ __forceinline__ float bf_hi(unsigned int w) { return __uint_as_float(w & 0xffff0000u); }

__device__ __forceinline__ float wred_sum(float s) {
    #pragma unroll
    for (int off = 1; off <= 32; off <<= 1) s += __shfl_xor(s, off, 64);
    return s;
}
__device__ __forceinline__ float wred_max(float s) {
    #pragma unroll
    for (int off = 1; off <= 32; off <<= 1) s = fmaxf(s, __shfl_xor(s, off, 64));
    return s;
}
__device__ __forceinline__ int wred_sumi(int s) {
    #pragma unroll
    for (int off = 1; off <= 32; off <<= 1) s += __shfl_xor(s, off, 64);
    return s;
}
__device__ __forceinline__ float dot8(uint4 a, uint4 b) {
    return bf_lo(a.x) * bf_lo(b.x) + bf_hi(a.x) * bf_hi(b.x)
         + bf_lo(a.y) * bf_lo(b.y) + bf_hi(a.y) * bf_hi(b.y)
         + bf_lo(a.z) * bf_lo(b.z) + bf_hi(a.z) * bf_hi(b.z)
         + bf_lo(a.w) * bf_lo(b.w) + bf_hi(a.w) * bf_hi(b.w);
}

// ---------------------------------------------------------------------------
// prep1: [0,4096) convert x -> bf16 AND zero 2KB of mask each |
//        [4096,4864) transpose-convert W -> Wt
// ---------------------------------------------------------------------------
__global__ __launch_bounds__(256) void prep1(
    const float* __restrict__ x, unsigned short* __restrict__ xb,
    const float* __restrict__ Wq, const float* __restrict__ Wk,
    const float* __restrict__ Wv, unsigned short* __restrict__ Wt,
    unsigned int* __restrict__ mask)
{
    __shared__ float sm[32][33];
    const int b = blockIdx.x;
    if (b < 4096) {
        int i = b * 256 + threadIdx.x;
        float4 f = ((const float4*)x)[i];
        ushort4 o;
        o.x = f2bf(f.x); o.y = f2bf(f.y); o.z = f2bf(f.z); o.w = f2bf(f.w);
        ((ushort4*)xb)[i] = o;
        // zero mask: 4096 blocks x 512 uints = 2M uints = 8MB
        ((uint2*)mask)[i] = make_uint2(0u, 0u);
    } else {
        int bb = b - 4096;
        int which = bb >> 8, t = bb & 255;
        const float* __restrict__ W = (which == 0) ? Wq : (which == 1) ? Wk : Wv;
        unsigned short* __restrict__ outp = Wt + (size_t)which * DIM * DIM;
        int n0 = (t & 15) * 32, k0 = (t >> 4) * 32;
        int tx = threadIdx.x & 31, ty = threadIdx.x >> 5;
        #pragma unroll
        for (int r = 0; r < 4; ++r)
            sm[ty + 8 * r][tx] = W[(size_t)(k0 + ty + 8 * r) * DIM + n0 + tx];
        __syncthreads();
        #pragma unroll
        for (int r = 0; r < 4; ++r)
            outp[(size_t)(n0 + ty + 8 * r) * DIM + k0 + tx] = f2bf(sm[tx][ty + 8 * r]);
    }
}

// prep2: edge scatter (needs fully-zeroed mask)
__global__ __launch_bounds__(256) void prep2(
    const int* __restrict__ ei, unsigned int* __restrict__ mask, int E)
{
    int e = blockIdx.x * 256 + threadIdx.x;
    if (e >= E) return;
    int src = ei[e];
    int dst = ei[E + e];
    atomicOr(&mask[(size_t)src * MASK_WORDS + (dst >> 5)], 1u << (dst & 31));
}

// ---------------------------------------------------------------------------
// bf16 MFMA GEMM, 128x128 tile, BK=32, global_load_lds staging.
// XCD swizzle: linear id p -> xcd = p%8 owns M-tiles [xcd*8, xcd*8+8) x all
// 12 N-tiles (N merged over q/k/v) => per-XCD L2 working set 1MB A + 1.5MB B.
// ---------------------------------------------------------------------------
__device__ __forceinline__ void load_lds16(const unsigned short* g, unsigned short* l) {
    __builtin_amdgcn_global_load_lds(
        (const __attribute__((address_space(1))) unsigned int*)g,
        (__attribute__((address_space(3))) unsigned int*)l, 16, 0, 0);
}

__global__ __launch_bounds__(256) void mfma_gemm(
    const unsigned short* __restrict__ xb, const unsigned short* __restrict__ Wt,
    const float* __restrict__ bq, const float* __restrict__ bk, const float* __restrict__ bv,
    unsigned short* __restrict__ qkv)
{
    // swizzle: p -> (m, n) with XCD locality
    const int p = blockIdx.x;
    const int xcd = p & 7;
    const int s = p >> 3;             // 0..95
    const int mloc = s / 12;          // 0..7
    const int n = s - 12 * mloc;      // 0..11
    const int which = n >> 2;
    const int row0 = (xcd * 8 + mloc) << 7;
    const int col0 = (n & 3) << 7;

    const unsigned short* __restrict__ Bm = Wt + (size_t)which * DIM * DIM;
    const float* __restrict__ bias = (which == 0) ? bq : (which == 1) ? bk : bv;
    unsigned short* __restrict__ outp = qkv + (size_t)which * N_NODES * DIM;

    const int tid = threadIdx.x;
    const int lane = tid & 63;
    const int w = tid >> 6;
    const int wm = (w >> 1) * 64;
    const int wn = (w & 1) * 64;
    const int L = lane & 15;
    const int quad = lane >> 4;

    __shared__ unsigned short As[128 * 32];   // chunk ch at byte ch*16
    __shared__ unsigned short Bs[128 * 32];

    f32x4 zero = {0.f, 0.f, 0.f, 0.f};
    f32x4 acc[4][4];
    #pragma unroll
    for (int i = 0; i < 4; ++i)
        #pragma unroll
        for (int j = 0; j < 4; ++j) acc[i][j] = zero;

    const int m0 = tid >> 2;
    const int ko = (tid & 3) << 3;

    for (int k0 = 0; k0 < DIM; k0 += 32) {
        load_lds16(xb + (size_t)(row0 + m0) * DIM + k0 + ko,      As + tid * 8);
        load_lds16(xb + (size_t)(row0 + 64 + m0) * DIM + k0 + ko, As + 2048 + tid * 8);
        load_lds16(Bm + (size_t)(col0 + m0) * DIM + k0 + ko,      Bs + tid * 8);
        load_lds16(Bm + (size_t)(col0 + 64 + m0) * DIM + k0 + ko, Bs + 2048 + tid * 8);
        __syncthreads();

        short8 a[4], bfr[4];
        #pragma unroll
        for (int i = 0; i < 4; ++i)
            a[i] = *(const short8*)(const void*)&As[(wm + i * 16 + L) * 32 + quad * 8];
        #pragma unroll
        for (int j = 0; j < 4; ++j)
            bfr[j] = *(const short8*)(const void*)&Bs[(wn + j * 16 + L) * 32 + quad * 8];

        #pragma unroll
        for (int i = 0; i < 4; ++i)
            #pragma unroll
            for (int j = 0; j < 4; ++j)
                acc[i][j] = __builtin_amdgcn_mfma_f32_16x16x32_bf16(a[i], bfr[j], acc[i][j], 0, 0, 0);
        __syncthreads();
    }

    float biasv[4];
    #pragma unroll
    for (int j = 0; j < 4; ++j) biasv[j] = bias[col0 + wn + j * 16 + L];
    #pragma unroll
    for (int i = 0; i < 4; ++i) {
        int r0 = row0 + wm + i * 16 + quad * 4;
        #pragma unroll
        for (int j = 0; j < 4; ++j) {
            int c = col0 + wn + j * 16 + L;
            #pragma unroll
            for (int r = 0; r < 4; ++r)
                outp[(size_t)(r0 + r) * DIM + c] = f2bf(acc[i][j][r] + biasv[j]);
        }
    }
}

// ---------------------------------------------------------------------------
// attention: one row per 256-thr block, 4 waves = 4 mask slices (64 words
// each, one word per lane). Each wave does a slice-local online softmax;
// slices merged at the end (2 barriers). Per-slice chunking (8 subchunks of
// 8 words) keeps LDS small yet exact for any degree.
// ---------------------------------------------------------------------------
__global__ __launch_bounds__(256) void attn_kernel(
    const unsigned short* __restrict__ q, const unsigned short* __restrict__ k,
    const unsigned short* __restrict__ v, const unsigned int* __restrict__ mask,
    float* __restrict__ out)
{
    __shared__ unsigned short nbr[4][SCAP];   // 2KB
    __shared__ float pw[4][SCAP];             // 4KB
    __shared__ float buf[4][DIM];             // 8KB merge buffer
    __shared__ float sm_m[4], sm_l[4];
    __shared__ int degs[4];
    __shared__ int cnt[4];

    const int tid = threadIdx.x;
    const int lane = tid & 63;
    const int wid = tid >> 6;
    const int row = blockIdx.x;

    const uint4 qv = *(const uint4*)(q + (size_t)row * DIM + lane * 8);
    const unsigned int mw = mask[(size_t)row * MASK_WORDS + wid * 64 + lane];

    const int pc_s = wred_sumi(__popc(mw));     // slice degree
    if (lane == 0) degs[wid] = pc_s;
    __syncthreads();
    const int total = degs[0] + degs[1] + degs[2] + degs[3];

    float o[8];
    #pragma unroll
    for (int i = 0; i < 8; ++i) o[i] = 0.f;

    if (total == 0) {
        // all-NEG row -> uniform 1/N over all v rows (prob ~0, exactness only)
        for (int j = wid * 2048; j < (wid + 1) * 2048; ++j) {
            uint4 vv = *(const uint4*)(v + (size_t)j * DIM + lane * 8);
            o[0] += bf_lo(vv.x); o[1] += bf_hi(vv.x);
            o[2] += bf_lo(vv.y); o[3] += bf_hi(vv.y);
            o[4] += bf_lo(vv.z); o[5] += bf_hi(vv.z);
            o[6] += bf_lo(vv.w); o[7] += bf_hi(vv.w);
        }
        #pragma unroll
        for (int i = 0; i < 8; ++i) buf[wid][lane * 8 + i] = o[i];
        __syncthreads();
        const float sc = 1.0f / N_NODES;
        int c = tid * 2;
        float2 r;
        r.x = (buf[0][c] + buf[1][c] + buf[2][c] + buf[3][c]) * sc;
        r.y = (buf[0][c + 1] + buf[1][c + 1] + buf[2][c + 1] + buf[3][c + 1]) * sc;
        *(float2*)(out + (size_t)row * DIM + c) = r;
        return;
    }

    const float scale = 0.044194173824159220f;   // 1/sqrt(512)
    float m_run = -3.0e38f, l_run = 0.f;

    const int nchunks = (pc_s <= SCAP) ? 1 : 8;
    for (int c = 0; c < nchunks; ++c) {
        if (lane == 0) cnt[wid] = 0;
        // scan: single chunk -> every lane's word; multi -> lanes [c*8,c*8+8)
        if (nchunks == 1 || (lane >> 3) == c) {
            unsigned int ww = mw;
            while (ww) {
                int bpos = __ffs(ww) - 1; ww &= ww - 1;
                int pos = atomicAdd(&cnt[wid], 1);
                nbr[wid][pos] = (unsigned short)((wid * 64 + lane) * 32 + bpos);
            }
        }
        const int cn = cnt[wid];
        if (cn == 0) continue;

        // scores, 4-wide for memory-level parallelism
        for (int p0 = 0; p0 < cn; p0 += 4) {
            int j0 = nbr[wid][p0];
            int j1 = nbr[wid][(p0 + 1 < cn) ? p0 + 1 : p0];
            int j2 = nbr[wid][(p0 + 2 < cn) ? p0 + 2 : p0];
            int j3 = nbr[wid][(p0 + 3 < cn) ? p0 + 3 : p0];
            uint4 k0v = *(const uint4*)(k + (size_t)j0 * DIM + lane * 8);
            uint4 k1v = *(const uint4*)(k + (size_t)j1 * DIM + lane * 8);
            uint4 k2v = *(const uint4*)(k + (size_t)j2 * DIM + lane * 8);
            uint4 k3v = *(const uint4*)(k + (size_t)j3 * DIM + lane * 8);
            float s0 = wred_sum(dot8(qv, k0v));
            float s1 = wred_sum(dot8(qv, k1v));
            float s2 = wred_sum(dot8(qv, k2v));
            float s3 = wred_sum(dot8(qv, k3v));
            if (lane == 0) {
                pw[wid][p0] = s0 * scale;
                if (p0 + 1 < cn) pw[wid][p0 + 1] = s1 * scale;
                if (p0 + 2 < cn) pw[wid][p0 + 2] = s2 * scale;
                if (p0 + 3 < cn) pw[wid][p0 + 3] = s3 * scale;
            }
        }

        // slice-chunk softmax (wave-local)
        float mc = -3.0e38f;
        for (int p = lane; p < cn; p += 64) mc = fmaxf(mc, pw[wid][p]);
        mc = wred_max(mc);
        const float mnew = fmaxf(m_run, mc);
        const float f = __expf(m_run - mnew);
        float ls = 0.f;
        for (int p = lane; p < cn; p += 64) {
            float e = __expf(pw[wid][p] - mnew);
            pw[wid][p] = e;
            ls += e;
        }
        l_run = l_run * f + wred_sum(ls);
        m_run = mnew;
        #pragma unroll
        for (int i = 0; i < 8; ++i) o[i] *= f;

        // weighted v accumulation, 4-wide (clamped lanes get weight 0)
        for (int p0 = 0; p0 < cn; p0 += 4) {
            int j0 = nbr[wid][p0];
            int j1 = nbr[wid][(p0 + 1 < cn) ? p0 + 1 : p0];
            int j2 = nbr[wid][(p0 + 2 < cn) ? p0 + 2 : p0];
            int j3 = nbr[wid][(p0 + 3 < cn) ? p0 + 3 : p0];
            float w0 = pw[wid][p0];
            float w1 = (p0 + 1 < cn) ? pw[wid][p0 + 1] : 0.f;
            float w2 = (p0 + 2 < cn) ? pw[wid][p0 + 2] : 0.f;
            float w3 = (p0 + 3 < cn) ? pw[wid][p0 + 3] : 0.f;
            uint4 v0 = *(const uint4*)(v + (size_t)j0 * DIM + lane * 8);
            uint4 v1 = *(const uint4*)(v + (size_t)j1 * DIM + lane * 8);
            uint4 v2 = *(const uint4*)(v + (size_t)j2 * DIM + lane * 8);
            uint4 v3 = *(const uint4*)(v + (size_t)j3 * DIM + lane * 8);
            o[0] += w0 * bf_lo(v0.x) + w1 * bf_lo(v1.x) + w2 * bf_lo(v2.x) + w3 * bf_lo(v3.x);
            o[1] += w0 * bf_hi(v0.x) + w1 * bf_hi(v1.x) + w2 * bf_hi(v2.x) + w3 * bf_hi(v3.x);
            o[2] += w0 * bf_lo(v0.y) + w1 * bf_lo(v1.y) + w2 * bf_lo(v2.y) + w3 * bf_lo(v3.y);
            o[3] += w0 * bf_hi(v0.y) + w1 * bf_hi(v1.y) + w2 * bf_hi(v2.y) + w3 * bf_hi(v3.y);
            o[4] += w0 * bf_lo(v0.z) + w1 * bf_lo(v1.z) + w2 * bf_lo(v2.z) + w3 * bf_lo(v3.z);
            o[5] += w0 * bf_hi(v0.z) + w1 * bf_hi(v1.z) + w2 * bf_hi(v2.z) + w3 * bf_hi(v3.z);
            o[6] += w0 * bf_lo(v0.w) + w1 * bf_lo(v1.w) + w2 * bf_lo(v2.w) + w3 * bf_lo(v3.w);
            o[7] += w0 * bf_hi(v0.w) + w1 * bf_hi(v1.w) + w2 * bf_hi(v2.w) + w3 * bf_hi(v3.w);
        }
    }

    // merge 4 slices: global max, rescale, sum
    if (lane == 0) { sm_m[wid] = m_run; sm_l[wid] = l_run; }
    __syncthreads();
    const float M = fmaxf(fmaxf(sm_m[0], sm_m[1]), fmaxf(sm_m[2], sm_m[3]));
    const float Lsum = sm_l[0] * __expf(sm_m[0] - M) + sm_l[1] * __expf(sm_m[1] - M)
                     + sm_l[2] * __expf(sm_m[2] - M) + sm_l[3] * __expf(sm_m[3] - M);
    const float r = __expf(m_run - M);   // 0 if this slice was empty
    #pragma unroll
    for (int i = 0; i < 8; ++i) buf[wid][lane * 8 + i] = o[i] * r;
    __syncthreads();

    const float inv = 1.0f / Lsum;
    int c = tid * 2;
    float2 res;
    res.x = (buf[0][c] + buf[1][c] + buf[2][c] + buf[3][c]) * inv;
    res.y = (buf[0][c + 1] + buf[1][c + 1] + buf[2][c + 1] + buf[3][c + 1]) * inv;
    *(float2*)(out + (size_t)row * DIM + c) = res;
}

// ---------------------------------------------------------------------------
extern "C" void kernel_launch(void* const* d_in, const int* in_sizes, int n_in,
                              void* d_out, int out_size, void* d_ws, size_t ws_size,
                              hipStream_t stream)
{
    const float* x  = (const float*)d_in[0];
    const int*   ei = (const int*)d_in[1];
    const float* Wq = (const float*)d_in[2];
    const float* bq = (const float*)d_in[3];
    const float* Wk = (const float*)d_in[4];
    const float* bk = (const float*)d_in[5];
    const float* Wv = (const float*)d_in[6];
    const float* bv = (const float*)d_in[7];
    float* out = (float*)d_out;

    const int E = in_sizes[1] / 2;
    const size_t NM = (size_t)N_NODES * DIM;

    unsigned short* xb = (unsigned short*)d_ws;
    unsigned short* Wt = xb + NM;
    unsigned short* qkv = Wt + (size_t)3 * DIM * DIM;   // q | k | v contiguous
    unsigned short* qb = qkv;
    unsigned short* kb = qkv + NM;
    unsigned short* vb = qkv + 2 * NM;
    unsigned int* mask = (unsigned int*)(qkv + 3 * NM);

    prep1<<<4864, 256, 0, stream>>>(x, xb, Wq, Wk, Wv, Wt, mask);
    prep2<<<(E + 255) / 256, 256, 0, stream>>>(ei, mask, E);

    mfma_gemm<<<768, 256, 0, stream>>>(xb, Wt, bq, bk, bv, qkv);

    attn_kernel<<<N_NODES, 256, 0, stream>>>(qb, kb, vb, mask, out);
}